// Round 7
// baseline (19228.748 us; speedup 1.0000x reference)
//
#include <hip/hip_runtime.h>
#include <hip/hip_cooperative_groups.h>
#include <math.h>

namespace cg = cooperative_groups;

#define S_   256
#define B_   32
#define H_   512
#define E_   256
#define V_   10000
#define K_   3
#define T_   32
#define N1_  96
#define BOS_ 1
#define EOS_ 1
#define NEG_ (-1000000000.0f)
#define RT   4
#define LG_MT 79            // ceil(10000/128)
#define GST2 (N1_ * 2048)   // gts k-part stride (floats)
#define NB   256            // persistent grid size

// ---------------------------------------------------------------------------
// fp32 tiled GEMM for the 3 prologue launches (h0, c0, encp). 64x64 tile.
// ---------------------------------------------------------------------------
__global__ __launch_bounds__(256) void gemm_k(
    const float* __restrict__ A, const float* __restrict__ B1,
    const float* __restrict__ bias1, float* __restrict__ C,
    int N, int Kd, int M)
{
  __shared__ float As[16][64];
  __shared__ float Bs[16][64];
  const int tid = threadIdx.x;
  const int m0 = blockIdx.x * 64;
  const int n0 = blockIdx.y * 64;
  const int tm = tid & 15, tn = tid >> 4;
  const int la_n = tid & 63;
  const int la_k = (tid >> 6) * 4;
  const int lb_m = (tid & 15) * 4;
  const int lb_k = tid >> 4;
  const int an = (n0 + la_n < N) ? (n0 + la_n) : 0;
  const float* Arow = A + (size_t)an * Kd;

  float4 a_reg = *(const float4*)(Arow + la_k);
  float4 b_reg = *(const float4*)(B1 + (size_t)lb_k * M + m0 + lb_m);
  float acc[4][4] = {};

  for (int k0 = 0; k0 < Kd; k0 += 16) {
    if (k0) __syncthreads();
    As[la_k + 0][la_n] = a_reg.x; As[la_k + 1][la_n] = a_reg.y;
    As[la_k + 2][la_n] = a_reg.z; As[la_k + 3][la_n] = a_reg.w;
    *(float4*)&Bs[lb_k][lb_m] = b_reg;
    __syncthreads();
    if (k0 + 16 < Kd) {
      a_reg = *(const float4*)(Arow + (k0 + 16) + la_k);
      b_reg = *(const float4*)(B1 + (size_t)(k0 + 16 + lb_k) * M + m0 + lb_m);
    }
#pragma unroll
    for (int kk = 0; kk < 16; kk++) {
      float4 av = *(const float4*)&As[kk][tn * 4];
      float4 bv = *(const float4*)&Bs[kk][tm * 4];
      float a[4] = {av.x, av.y, av.z, av.w};
      float b[4] = {bv.x, bv.y, bv.z, bv.w};
#pragma unroll
      for (int i = 0; i < 4; i++)
#pragma unroll
        for (int j = 0; j < 4; j++) acc[i][j] += a[i] * b[j];
    }
  }
#pragma unroll
  for (int i = 0; i < 4; i++) {
    int n = n0 + tn * 4 + i;
    if (n >= N) continue;
#pragma unroll
    for (int j = 0; j < 4; j++) {
      int m = m0 + tm * 4 + j;
      float v = acc[i][j];
      if (bias1) v += bias1[m];
      C[(size_t)n * M + m] = v;
    }
  }
}

// ---- top-k helpers (jax tie-break: value desc, then smaller index) ----
__device__ __forceinline__ bool tk_better(float va, int ia, float vb, int ib) {
  return (va > vb) || (va == vb && ia < ib);
}
__device__ __forceinline__ void tk_insertN(float v, int i, float* vv, int* ii) {
  if (!tk_better(v, i, vv[RT - 1], ii[RT - 1])) return;
  vv[RT - 1] = v; ii[RT - 1] = i;
#pragma unroll
  for (int q = RT - 1; q > 0; q--) {
    if (tk_better(vv[q], ii[q], vv[q - 1], ii[q - 1])) {
      float tv = vv[q]; vv[q] = vv[q - 1]; vv[q - 1] = tv;
      int ti = ii[q]; ii[q] = ii[q - 1]; ii[q - 1] = ti;
    }
  }
}
__device__ __forceinline__ void tk_merge_reg(float* av, int* ai,
                                             const float* bv2, const int* bi2) {
  float rv[RT]; int ri[RT];
  int p = 0, q = 0;
#pragma unroll
  for (int t = 0; t < RT; t++) {
    bool ta;
    if (p >= RT) ta = false;
    else if (q >= RT) ta = true;
    else ta = tk_better(av[p], ai[p], bv2[q], bi2[q]);
    if (ta) { rv[t] = av[p]; ri[t] = ai[p]; p++; }
    else    { rv[t] = bv2[q]; ri[t] = bi2[q]; q++; }
  }
#pragma unroll
  for (int t = 0; t < RT; t++) { av[t] = rv[t]; ai[t] = ri[t]; }
}
__device__ __forceinline__ void tk_merge_lds(float* sv, int* si, int a, int b) {
  float rv[RT]; int ri[RT];
  int p = 0, q = 0;
#pragma unroll
  for (int t = 0; t < RT; t++) {
    bool ta;
    if (p >= RT) ta = false;
    else if (q >= RT) ta = true;
    else ta = tk_better(sv[a + p], si[a + p], sv[b + q], si[b + q]);
    if (ta) { rv[t] = sv[a + p]; ri[t] = si[a + p]; p++; }
    else    { rv[t] = sv[b + q]; ri[t] = si[b + q]; q++; }
  }
#pragma unroll
  for (int t = 0; t < RT; t++) { sv[a + t] = rv[t]; si[a + t] = ri[t]; }
}

__device__ __forceinline__ float sigf(float x) { return 1.f / (1.f + expf(-x)); }

struct BP {
  const float *enc, *mask, *emb, *Wp, *Wv, *Wih, *Whh, *bih, *bhh, *Wc, *bc;
  float *encp, *hb, *cb, *h2, *c2, *pp, *sc, *xc, *gts, *ptv, *pmx, *psm;
  float *cumA, *cumB, *out;
  int *pti, *eosA, *eosB, *pA, *pB;
};

// ======================= phase device functions =======================

// init: ex = emb[BOS], pp = h0 @ Wp for rows 0..31. needs sF[1024].
__device__ void ph_init(const BP& p, int bid, int tid, float* sF)
{
  if (bid < B_) {
    const int b = bid;
    p.xc[(size_t)b * 768 + tid] = p.emb[(size_t)BOS_ * E_ + tid];  // tid<256
    sF[tid] = p.hb[(size_t)b * H_ + tid];
    sF[256 + tid] = p.hb[(size_t)b * H_ + 256 + tid];
    __syncthreads();
#pragma unroll
    for (int o = 0; o < 2; o++) {
      int m = tid + o * 256;
      float acc = 0.f;
#pragma unroll 4
      for (int k = 0; k < H_; k++) acc += sF[k] * p.Wp[(size_t)k * H_ + m];
      p.pp[(size_t)b * H_ + m] = acc;
    }
  }
}

// A: masked scores sc[n][s]. tasks 8*N. needs sF[1024].
__device__ void ph_A(const BP& p, int t, int bid0, int stride, int tid, float* sF)
{
  const int N = t ? N1_ : B_;
  const int bdiv = t ? K_ : 1;
  for (int u = bid0; u < 8 * N; u += stride) {
    const int n = u >> 3, st = u & 7;
    const int b = n / bdiv;
    float* ppS = sF;
    float* WvS = sF + 512;
    ppS[tid] = p.pp[(size_t)n * H_ + tid];
    ppS[256 + tid] = p.pp[(size_t)n * H_ + 256 + tid];
    WvS[tid] = p.Wv[tid];
    WvS[256 + tid] = p.Wv[256 + tid];
    __syncthreads();
    const int w = tid >> 6, lane = tid & 63;
#pragma unroll
    for (int j = 0; j < 8; j++) {
      int s = st * 32 + w * 8 + j;
      const float* ep = p.encp + ((size_t)s * B_ + b) * H_;
      float acc = 0.f;
#pragma unroll
      for (int r = 0; r < 8; r++) {
        int hh = r * 64 + lane;
        acc += tanhf(ppS[hh] + ep[hh]) * WvS[hh];
      }
#pragma unroll
      for (int off = 32; off; off >>= 1) acc += __shfl_xor(acc, off);
      if (lane == 0)
        p.sc[(size_t)n * S_ + s] =
            (p.mask[(size_t)b * S_ + s] == 0.f) ? NEG_ : acc;
    }
    __syncthreads();
  }
}

// B: softmax + ctx slice -> xc[256..768). tasks 8*N. needs sF[512].
__device__ void ph_B(const BP& p, int t, int bid0, int stride, int tid, float* sF)
{
  const int N = t ? N1_ : B_;
  const int bdiv = t ? K_ : 1;
  for (int u = bid0; u < 8 * N; u += stride) {
    const int n = u >> 3, ht = u & 7;
    const int b = n / bdiv;
    const int h0 = ht * 64;
    float* aS = sF;
    float* red = sF + 256;
    float v = p.sc[(size_t)n * S_ + tid];
    red[tid] = v; __syncthreads();
    for (int st = 128; st; st >>= 1) {
      if (tid < st) red[tid] = fmaxf(red[tid], red[tid + st]);
      __syncthreads();
    }
    const float mx = red[0]; __syncthreads();
    float e = expf(v - mx);
    aS[tid] = e; red[tid] = e; __syncthreads();
    for (int st = 128; st; st >>= 1) {
      if (tid < st) red[tid] += red[tid + st];
      __syncthreads();
    }
    const float rsum = 1.f / red[0];
    __syncthreads();
    const int sg = tid >> 6, col = tid & 63;
    float acc = 0.f;
#pragma unroll 4
    for (int s0 = 0; s0 < S_; s0 += 4)
      acc += aS[s0 + sg] * p.enc[((size_t)(s0 + sg) * B_ + b) * H_ + h0 + col];
    red[tid] = acc; __syncthreads();
    if (tid < 64) {
      float tot = red[tid] + red[64 + tid] + red[128 + tid] + red[192 + tid];
      p.xc[(size_t)n * 768 + 256 + h0 + tid] = tot * rsum;
    }
    __syncthreads();
  }
}

// C: gts = [ex|ctx|h] @ [Wih;Whh], 32x64 tiles, 2 k-parts. tasks 64*ntv.
// needs sF[1536].
__device__ void ph_C(const BP& p, int t, int bid0, int stride, int tid, float* sF)
{
  const int N = t ? N1_ : B_;
  const int ntv = N >> 5;
  for (int u = bid0; u < 64 * ntv; u += stride) {
    const int mt = u & 31;
    const int rest = u >> 5;
    const int nt = rest % ntv;
    const int kp = rest / ntv;
    const int m0 = mt * 64, n0 = nt * 32, kb = kp * 640;
    float* As = sF;
    float* Bs = sF + 512;
    const bool al = tid < 128;
    const int ar = tid & 31, ak = ((tid >> 5) & 3) * 4;
    const int bk = tid >> 4, bc4 = (tid & 15) * 4;
    const int tn = tid >> 4, tm = tid & 15;
    const int arow = n0 + ar;
    float4 aR = make_float4(0, 0, 0, 0), bR;
    {
      int k = kb + ak;
      if (al) aR = *(const float4*)((k < 768)
          ? (p.xc + (size_t)arow * 768 + k)
          : (p.hb + (size_t)arow * H_ + (k - 768)));
      int k2 = kb + bk;
      const float* Wr = (k2 < 768) ? (p.Wih + (size_t)k2 * 2048)
                                   : (p.Whh + (size_t)(k2 - 768) * 2048);
      bR = *(const float4*)(Wr + m0 + bc4);
    }
    float acc[2][4] = {};
    for (int it = 0; it < 40; it++) {
      if (it) __syncthreads();
      if (al) {
        As[(ak + 0) * 32 + ar] = aR.x; As[(ak + 1) * 32 + ar] = aR.y;
        As[(ak + 2) * 32 + ar] = aR.z; As[(ak + 3) * 32 + ar] = aR.w;
      }
      *(float4*)&Bs[bk * 64 + bc4] = bR;
      __syncthreads();
      if (it + 1 < 40) {
        int k0n = kb + (it + 1) * 16;
        int k = k0n + ak;
        if (al) aR = *(const float4*)((k < 768)
            ? (p.xc + (size_t)arow * 768 + k)
            : (p.hb + (size_t)arow * H_ + (k - 768)));
        int k2 = k0n + bk;
        const float* Wr = (k2 < 768) ? (p.Wih + (size_t)k2 * 2048)
                                     : (p.Whh + (size_t)(k2 - 768) * 2048);
        bR = *(const float4*)(Wr + m0 + bc4);
      }
#pragma unroll
      for (int kk = 0; kk < 16; kk++) {
        float a0 = As[kk * 32 + tn * 2];
        float a1 = As[kk * 32 + tn * 2 + 1];
        float4 bv = *(const float4*)&Bs[kk * 64 + tm * 4];
        acc[0][0] += a0 * bv.x; acc[0][1] += a0 * bv.y;
        acc[0][2] += a0 * bv.z; acc[0][3] += a0 * bv.w;
        acc[1][0] += a1 * bv.x; acc[1][1] += a1 * bv.y;
        acc[1][2] += a1 * bv.z; acc[1][3] += a1 * bv.w;
      }
    }
    float* gp = p.gts + (size_t)kp * GST2;
#pragma unroll
    for (int i = 0; i < 2; i++) {
      int row = n0 + tn * 2 + i;
#pragma unroll
      for (int j = 0; j < 4; j++)
        gp[(size_t)row * 2048 + m0 + tm * 4 + j] = acc[i][j];
    }
    __syncthreads();
  }
}

// D: LSTM pointwise. tasks N.
__device__ void ph_D(const BP& p, int t, int bid0, int stride, int tid)
{
  const int N = t ? N1_ : B_;
  for (int u = bid0; u < N; u += stride) {
    const int n = u;
#pragma unroll
    for (int o = 0; o < 2; o++) {
      int i = tid + o * 256;
      const float* gA = p.gts + (size_t)n * 2048;
      const float* gB = p.gts + GST2 + (size_t)n * 2048;
      float gi = gA[i] + gB[i] + p.bih[i] + p.bhh[i];
      float gf = gA[512 + i] + gB[512 + i] + p.bih[512 + i] + p.bhh[512 + i];
      float gc = gA[1024 + i] + gB[1024 + i] + p.bih[1024 + i] + p.bhh[1024 + i];
      float go = gA[1536 + i] + gB[1536 + i] + p.bih[1536 + i] + p.bhh[1536 + i];
      float cc = p.cb[(size_t)n * H_ + i];
      float cv = sigf(gf) * cc + sigf(gi) * tanhf(gc);
      float hv = sigf(go) * tanhf(cv);
      p.c2[(size_t)n * H_ + i] = cv;
      p.h2[(size_t)n * H_ + i] = hv;
    }
  }
}

// E: logits GEMM 32x128 + fused per-tile top-RT/max/expsum. tasks LG_MT*ntv.
// needs sF[2560].
__device__ void ph_E(const BP& p, int t, int bid0, int stride, int tid, float* sF)
{
  const int N = t ? N1_ : B_;
  const int ntv = N >> 5;
  for (int u = bid0; u < LG_MT * ntv; u += stride) {
    const int mt = u % LG_MT, nt = u / LG_MT;
    const int m0 = mt * 128, n0 = nt * 32;
    float* As = sF;
    float* Bs = sF + 512;
    const bool al = tid < 128;
    const int ar = tid & 31, ak = ((tid >> 5) & 3) * 4;
    const int tm = tid & 31, tn = tid >> 5;
    const int arow = n0 + ar;
    const bool edge = (m0 + 128 > V_);
    float4 aR[2]; float4 bR[2][2];
#pragma unroll
    for (int d = 0; d < 2; d++) {
      int k = d * 16 + ak;
      if (al) {
        const float* src = (k < 256) ? (p.xc + (size_t)arow * 768 + k)
                         : (k < 768) ? (p.h2 + (size_t)arow * H_ + (k - 256))
                                     : (p.xc + (size_t)arow * 768 + (k - 512));
        aR[d] = *(const float4*)src;
      }
#pragma unroll
      for (int l = 0; l < 2; l++) {
        int idx = l * 256 + tid;
        int kr = d * 16 + (idx >> 5), c4 = (idx & 31) * 4;
        const float* Wr = p.Wc + (size_t)kr * V_;
        if (!edge) bR[d][l] = *(const float4*)(Wr + m0 + c4);
        else {
          float4 bv;
          bv.x = (m0 + c4 + 0 < V_) ? Wr[m0 + c4 + 0] : 0.f;
          bv.y = (m0 + c4 + 1 < V_) ? Wr[m0 + c4 + 1] : 0.f;
          bv.z = (m0 + c4 + 2 < V_) ? Wr[m0 + c4 + 2] : 0.f;
          bv.w = (m0 + c4 + 3 < V_) ? Wr[m0 + c4 + 3] : 0.f;
          bR[d][l] = bv;
        }
      }
    }
    float acc[4][4] = {};
    for (int it = 0; it < 80; it++) {
      if (it) __syncthreads();
      const int sl = it & 1;
      if (al) {
        As[(ak + 0) * 32 + ar] = aR[sl].x; As[(ak + 1) * 32 + ar] = aR[sl].y;
        As[(ak + 2) * 32 + ar] = aR[sl].z; As[(ak + 3) * 32 + ar] = aR[sl].w;
      }
#pragma unroll
      for (int l = 0; l < 2; l++) {
        int idx = l * 256 + tid;
        *(float4*)&Bs[(idx >> 5) * 128 + (idx & 31) * 4] = bR[sl][l];
      }
      __syncthreads();
      if (it + 2 < 80) {
        int k0n = (it + 2) * 16;
        int k = k0n + ak;
        if (al) {
          const float* src = (k < 256) ? (p.xc + (size_t)arow * 768 + k)
                           : (k < 768) ? (p.h2 + (size_t)arow * H_ + (k - 256))
                                       : (p.xc + (size_t)arow * 768 + (k - 512));
          aR[sl] = *(const float4*)src;
        }
#pragma unroll
        for (int l = 0; l < 2; l++) {
          int idx = l * 256 + tid;
          int kr = k0n + (idx >> 5), c4 = (idx & 31) * 4;
          const float* Wr = p.Wc + (size_t)kr * V_;
          if (!edge) bR[sl][l] = *(const float4*)(Wr + m0 + c4);
          else {
            float4 bv;
            bv.x = (m0 + c4 + 0 < V_) ? Wr[m0 + c4 + 0] : 0.f;
            bv.y = (m0 + c4 + 1 < V_) ? Wr[m0 + c4 + 1] : 0.f;
            bv.z = (m0 + c4 + 2 < V_) ? Wr[m0 + c4 + 2] : 0.f;
            bv.w = (m0 + c4 + 3 < V_) ? Wr[m0 + c4 + 3] : 0.f;
            bR[sl][l] = bv;
          }
        }
      }
#pragma unroll
      for (int kk = 0; kk < 16; kk++) {
        float4 av = *(const float4*)&As[kk * 32 + tn * 4];
        float4 bv = *(const float4*)&Bs[kk * 128 + tm * 4];
        float a[4] = {av.x, av.y, av.z, av.w};
        float b[4] = {bv.x, bv.y, bv.z, bv.w};
#pragma unroll
        for (int i = 0; i < 4; i++)
#pragma unroll
          for (int j = 0; j < 4; j++) acc[i][j] += a[i] * b[j];
      }
    }
#pragma unroll
    for (int i = 0; i < 4; i++) {
      float vv[RT]; int ii[RT];
#pragma unroll
      for (int q = 0; q < RT; q++) { vv[q] = -3.4e38f; ii[q] = 0x7fffffff; }
      float vals[4];
#pragma unroll
      for (int j = 0; j < 4; j++) {
        int m = m0 + tm * 4 + j;
        float v = (m < V_) ? (acc[i][j] + p.bc[m]) : -3.4e38f;
        vals[j] = v;
        if (m < V_) tk_insertN(v, m, vv, ii);
      }
#pragma unroll
      for (int off = 1; off < 32; off <<= 1) {
        float ov[RT]; int oi[RT];
#pragma unroll
        for (int q = 0; q < RT; q++) {
          ov[q] = __shfl_xor(vv[q], off);
          oi[q] = __shfl_xor(ii[q], off);
        }
        tk_merge_reg(vv, ii, ov, oi);
      }
      const float rowmax = vv[0];
      float s = 0.f;
#pragma unroll
      for (int j = 0; j < 4; j++) {
        int m = m0 + tm * 4 + j;
        if (m < V_) s += expf(vals[j] - rowmax);
      }
#pragma unroll
      for (int off = 1; off < 32; off <<= 1) s += __shfl_xor(s, off);
      const int gr = n0 + tn * 4 + i;
      if (tm == 0 && gr < N) {
        const size_t pb = (size_t)gr * LG_MT + mt;
#pragma unroll
        for (int q = 0; q < RT; q++) {
          p.ptv[pb * RT + q] = vv[q]; p.pti[pb * RT + q] = ii[q];
        }
        p.pmx[pb] = rowmax;
        p.psm[pb] = s;
      }
    }
    __syncthreads();
  }
}

// F: merge partials + beam select + gather + ex + next pp. blocks 0..B_-1.
// needs sF[2208], sI[576].
__device__ void ph_F(const BP& p, int t, int bid, int tid, float* sF, int* sI)
{
  if (bid >= B_) return;
  const int b = bid;
  const float* cumOld = (t & 1) ? p.cumA : p.cumB;
  float* cumNew = (t & 1) ? p.cumB : p.cumA;
  const int* eosOld = (t & 1) ? p.eosA : p.eosB;
  int* eosNew = (t & 1) ? p.eosB : p.eosA;
  const int* pOld = (t & 1) ? p.pA : p.pB;
  int* pNew = (t & 1) ? p.pB : p.pA;
  float* sv = sF;
  float* red = sF + 512;
  float* rtvL = sF + 640;
  float* mgL = sF + 652;
  float* lsL = sF + 656;
  float* selV = sF + 660;
  float* hL = sF + 672;
  int* si = sI;
  int* rtiL = sI + 512;
  int* selG = sI + 524;
  int* selT = sI + 528;
  const int R = t ? 3 : 1;
  for (int r = 0; r < R; r++) {
    const int row = t ? (b * K_ + r) : b;
    float mx_t = -3.4e38f, sm_t = 0.f;
    if (tid < 128) {
      float vv[RT]; int ii[RT];
#pragma unroll
      for (int q = 0; q < RT; q++) { vv[q] = -3.4e38f; ii[q] = 0x7fffffff; }
      if (tid < LG_MT) {
        const size_t pb = (size_t)row * LG_MT + tid;
#pragma unroll
        for (int q = 0; q < RT; q++) {
          vv[q] = p.ptv[pb * RT + q]; ii[q] = p.pti[pb * RT + q];
        }
        mx_t = p.pmx[pb]; sm_t = p.psm[pb];
      }
#pragma unroll
      for (int q = 0; q < RT; q++) {
        sv[tid * RT + q] = vv[q]; si[tid * RT + q] = ii[q];
      }
      red[tid] = mx_t;
    }
    __syncthreads();
    for (int st = 64; st; st >>= 1) {
      if (tid < st) {
        tk_merge_lds(sv, si, tid * RT, (tid + st) * RT);
        red[tid] = fmaxf(red[tid], red[tid + st]);
      }
      __syncthreads();
    }
    const float Mg = red[0];
    __syncthreads();
    if (tid < 128) red[tid] = sm_t * expf(mx_t - Mg);
    __syncthreads();
    for (int st = 64; st; st >>= 1) {
      if (tid < st) red[tid] += red[tid + st];
      __syncthreads();
    }
    if (tid < RT) { rtvL[r * RT + tid] = sv[tid]; rtiL[r * RT + tid] = si[tid]; }
    if (tid == 0) { mgL[r] = Mg; lsL[r] = logf(red[0]); }
    __syncthreads();
  }
  if (tid == 0) {
    if (t == 0) {
      for (int r = 0; r < K_; r++) {
        selV[r] = (rtvL[r] - mgL[0]) - lsL[0];
        selT[r] = rtiL[r];
        selG[r] = b;
      }
    } else {
      float cv[3 * RT]; int cj[3 * RT]; int cnt = 0;
      for (int k = 0; k < K_; k++) {
        int row = b * K_ + k;
        float ck = cumOld[row];
        if (eosOld[row]) {
          cv[cnt] = ck; cj[cnt] = k * V_ + EOS_; cnt++;
        } else {
          for (int q = 0; q < RT; q++) {
            cv[cnt] = ck + ((rtvL[k * RT + q] - mgL[k]) - lsL[k]);
            cj[cnt] = k * V_ + rtiL[k * RT + q]; cnt++;
          }
        }
      }
      int used = 0;
      for (int r = 0; r < K_; r++) {
        int pick = -1;
        for (int i2 = 0; i2 < cnt; i2++) {
          if ((used >> i2) & 1) continue;
          if (pick < 0 || tk_better(cv[i2], cj[i2], cv[pick], cj[pick]))
            pick = i2;
        }
        used |= 1 << pick;
        selV[r] = cv[pick];
        selG[r] = b * K_ + cj[pick] / V_;
        selT[r] = cj[pick] % V_;
      }
    }
  }
  __syncthreads();
  for (int r = 0; r < K_; r++) {
    const int n = b * K_ + r, g = selG[r], tk2 = selT[r];
#pragma unroll
    for (int o = 0; o < 2; o++) {
      int i = tid + o * 256;
      float hv = p.h2[(size_t)g * H_ + i];
      p.hb[(size_t)n * H_ + i] = hv;
      hL[r * 512 + i] = hv;
      p.cb[(size_t)n * H_ + i] = p.c2[(size_t)g * H_ + i];
    }
    p.xc[(size_t)n * 768 + tid] = p.emb[(size_t)tk2 * E_ + tid];
  }
  if (tid < 96) {
    int tt = tid / 3, r = tid % 3;
    int n = b * K_ + r, g = selG[r];
    if (t == 0) pNew[tt * N1_ + n] = (tt == 0) ? selT[r] : 0;
    else        pNew[tt * N1_ + n] = (tt == t) ? selT[r] : pOld[tt * N1_ + g];
  }
  if (tid < K_) {
    int n = b * K_ + tid;
    cumNew[n] = selV[tid];
    eosNew[n] = (t == 0) ? (selT[tid] == EOS_ ? 1 : 0)
                         : ((eosOld[selG[tid]] | (selT[tid] == EOS_)) ? 1 : 0);
  }
  __syncthreads();
  for (int oi = tid; oi < K_ * H_; oi += 256) {
    int r = oi >> 9, m = oi & 511;
    float acc = 0.f;
#pragma unroll 4
    for (int k = 0; k < H_; k++) acc += hL[r * 512 + k] * p.Wp[(size_t)k * H_ + m];
    p.pp[(size_t)(b * K_ + r) * H_ + m] = acc;
  }
}

// final output. block 0 only.
__device__ void ph_out(const BP& p, int bid, int tid)
{
  if (bid != 0) return;
  for (int i = tid; i < T_ * B_ + N1_; i += 256) {
    if (i < T_ * B_) {
      int tt = i >> 5, b = i & 31;
      p.out[i] = (float)p.pB[tt * N1_ + b * K_];
    } else {
      p.out[i] = p.cumB[i - T_ * B_];
    }
  }
}

// ======================= cooperative kernel =======================
__global__ __launch_bounds__(256, 2) void beam_k(BP p)
{
  cg::grid_group gg = cg::this_grid();
  __shared__ float sF[2880];
  __shared__ int   sI[576];
  const int bid = blockIdx.x, tid = threadIdx.x;
  ph_init(p, bid, tid, sF);
  gg.sync();
  for (int t = 0; t < T_; t++) {
    ph_A(p, t, bid, (int)gridDim.x, tid, sF); gg.sync();
    ph_B(p, t, bid, (int)gridDim.x, tid, sF); gg.sync();
    ph_C(p, t, bid, (int)gridDim.x, tid, sF); gg.sync();
    ph_D(p, t, bid, (int)gridDim.x, tid);     gg.sync();
    ph_E(p, t, bid, (int)gridDim.x, tid, sF); gg.sync();
    ph_F(p, t, bid, tid, sF, sI);             gg.sync();
  }
  ph_out(p, bid, tid);
}

// ======================= fallback per-phase kernels =======================
__global__ __launch_bounds__(256) void fb_init_k(BP p) {
  __shared__ float sF[1024];
  ph_init(p, blockIdx.x, threadIdx.x, sF);
}
__global__ __launch_bounds__(256) void fb_A_k(BP p, int t) {
  __shared__ float sF[1024];
  ph_A(p, t, blockIdx.x, (int)gridDim.x, threadIdx.x, sF);
}
__global__ __launch_bounds__(256) void fb_B_k(BP p, int t) {
  __shared__ float sF[512];
  ph_B(p, t, blockIdx.x, (int)gridDim.x, threadIdx.x, sF);
}
__global__ __launch_bounds__(256) void fb_C_k(BP p, int t) {
  __shared__ float sF[1536];
  ph_C(p, t, blockIdx.x, (int)gridDim.x, threadIdx.x, sF);
}
__global__ __launch_bounds__(256) void fb_D_k(BP p, int t) {
  ph_D(p, t, blockIdx.x, (int)gridDim.x, threadIdx.x);
}
__global__ __launch_bounds__(256) void fb_E_k(BP p, int t) {
  __shared__ float sF[2560];
  ph_E(p, t, blockIdx.x, (int)gridDim.x, threadIdx.x, sF);
}
__global__ __launch_bounds__(256) void fb_F_k(BP p, int t) {
  __shared__ float sF[2208];
  __shared__ int   sI[576];
  ph_F(p, t, blockIdx.x, threadIdx.x, sF, sI);
}
__global__ __launch_bounds__(256) void fb_out_k(BP p) {
  ph_out(p, blockIdx.x, threadIdx.x);
}

// ---------------------------------------------------------------------------
extern "C" void kernel_launch(void* const* d_in, const int* in_sizes, int n_in,
                              void* d_out, int out_size, void* d_ws, size_t ws_size,
                              hipStream_t stream)
{
  const float* enc    = (const float*)d_in[0];
  const float* last_h = (const float*)d_in[1];
  const float* last_c = (const float*)d_in[2];
  const float* mask   = (const float*)d_in[3];
  const float* emb    = (const float*)d_in[5];
  const float* Wp     = (const float*)d_in[6];
  const float* We     = (const float*)d_in[7];
  const float* Wv     = (const float*)d_in[8];
  const float* W_ih   = (const float*)d_in[9];
  const float* W_hh   = (const float*)d_in[10];
  const float* b_ih   = (const float*)d_in[11];
  const float* b_hh   = (const float*)d_in[12];
  const float* Wc     = (const float*)d_in[13];
  const float* bc     = (const float*)d_in[14];
  const float* W_init = (const float*)d_in[15];
  const float* b_init = (const float*)d_in[16];

  // ws carve — ~20 MB unconditional (< proven 23.69 MB)
  float* w = (float*)d_ws;
  float* encp = w;  w += (size_t)S_ * B_ * H_;
  float* hb   = w;  w += N1_ * H_;
  float* cb   = w;  w += N1_ * H_;
  float* h2   = w;  w += N1_ * H_;
  float* c2   = w;  w += N1_ * H_;
  float* pp   = w;  w += N1_ * H_;
  float* sc   = w;  w += N1_ * S_;
  float* xc   = w;  w += N1_ * 768;
  float* gts  = w;  w += 2 * GST2;
  float* ptv  = w;  w += (size_t)N1_ * LG_MT * RT;
  float* pmx  = w;  w += (size_t)N1_ * LG_MT;
  float* psm  = w;  w += (size_t)N1_ * LG_MT;
  float* cumA = w;  w += N1_;
  float* cumB = w;  w += N1_;
  int* pti  = (int*)w;  w += (size_t)N1_ * LG_MT * RT;
  int* eosA = (int*)w;  w += N1_;
  int* eosB = (int*)w;  w += N1_;
  int* pA   = (int*)w;  w += T_ * N1_;
  int* pB   = (int*)w;  w += T_ * N1_;

  // prologue: h0, c0, enc_proj
  gemm_k<<<dim3(8, 1), 256, 0, stream>>>(last_h + B_ * H_, W_init, b_init,
                                         hb, B_, H_, H_);
  gemm_k<<<dim3(8, 1), 256, 0, stream>>>(last_c + B_ * H_, W_init, b_init,
                                         cb, B_, H_, H_);
  gemm_k<<<dim3(8, 128), 256, 0, stream>>>(enc, We, nullptr,
                                           encp, S_ * B_, H_, H_);

  BP prm;
  prm.enc = enc; prm.mask = mask; prm.emb = emb; prm.Wp = Wp; prm.Wv = Wv;
  prm.Wih = W_ih; prm.Whh = W_hh; prm.bih = b_ih; prm.bhh = b_hh;
  prm.Wc = Wc; prm.bc = bc;
  prm.encp = encp; prm.hb = hb; prm.cb = cb; prm.h2 = h2; prm.c2 = c2;
  prm.pp = pp; prm.sc = sc; prm.xc = xc; prm.gts = gts;
  prm.ptv = ptv; prm.pmx = pmx; prm.psm = psm;
  prm.cumA = cumA; prm.cumB = cumB; prm.out = (float*)d_out;
  prm.pti = pti; prm.eosA = eosA; prm.eosB = eosB; prm.pA = pA; prm.pB = pB;

  void* args[] = { &prm };
  hipError_t ce = hipLaunchCooperativeKernel((const void*)beam_k, dim3(NB),
                                             dim3(256), args, 0, stream);
  if (ce != hipSuccess) {
    (void)hipGetLastError();   // clear sticky error; take the split path
    fb_init_k<<<B_, 256, 0, stream>>>(prm);
    for (int t = 0; t < T_; t++) {
      const int N = t ? N1_ : B_;
      const int ntv = N >> 5;
      fb_A_k<<<8 * N, 256, 0, stream>>>(prm, t);
      fb_B_k<<<8 * N, 256, 0, stream>>>(prm, t);
      fb_C_k<<<64 * ntv, 256, 0, stream>>>(prm, t);
      fb_D_k<<<N, 256, 0, stream>>>(prm, t);
      fb_E_k<<<LG_MT * ntv, 256, 0, stream>>>(prm, t);
      fb_F_k<<<B_, 256, 0, stream>>>(prm, t);
    }
    fb_out_k<<<1, 256, 0, stream>>>(prm);
  }
}

// Round 8
// 14781.474 us; speedup vs baseline: 1.3009x; 1.3009x over previous
//
#include <hip/hip_runtime.h>
#include <math.h>

#define S_   256
#define B_   32
#define H_   512
#define E_   256
#define V_   10000
#define K_   3
#define T_   32
#define N1_  96
#define BOS_ 1
#define EOS_ 1
#define NEG_ (-1000000000.0f)
#define RT   4
#define LG_MT 79            // ceil(10000/128)
#define GST2 (N1_ * 2048)   // gts k-part stride (floats)

// ---------------------------------------------------------------------------
// fp32 tiled GEMM for the 3 prologue launches (h0, c0, encp). 64x64 tile.
// ---------------------------------------------------------------------------
__global__ __launch_bounds__(256) void gemm_k(
    const float* __restrict__ A, const float* __restrict__ B1,
    const float* __restrict__ bias1, float* __restrict__ C,
    int N, int Kd, int M)
{
  __shared__ float As[16][64];
  __shared__ float Bs[16][64];
  const int tid = threadIdx.x;
  const int m0 = blockIdx.x * 64;
  const int n0 = blockIdx.y * 64;
  const int tm = tid & 15, tn = tid >> 4;
  const int la_n = tid & 63;
  const int la_k = (tid >> 6) * 4;
  const int lb_m = (tid & 15) * 4;
  const int lb_k = tid >> 4;
  const int an = (n0 + la_n < N) ? (n0 + la_n) : 0;
  const float* Arow = A + (size_t)an * Kd;

  float4 a_reg = *(const float4*)(Arow + la_k);
  float4 b_reg = *(const float4*)(B1 + (size_t)lb_k * M + m0 + lb_m);
  float acc[4][4] = {};

  for (int k0 = 0; k0 < Kd; k0 += 16) {
    if (k0) __syncthreads();
    As[la_k + 0][la_n] = a_reg.x; As[la_k + 1][la_n] = a_reg.y;
    As[la_k + 2][la_n] = a_reg.z; As[la_k + 3][la_n] = a_reg.w;
    *(float4*)&Bs[lb_k][lb_m] = b_reg;
    __syncthreads();
    if (k0 + 16 < Kd) {
      a_reg = *(const float4*)(Arow + (k0 + 16) + la_k);
      b_reg = *(const float4*)(B1 + (size_t)(k0 + 16 + lb_k) * M + m0 + lb_m);
    }
#pragma unroll
    for (int kk = 0; kk < 16; kk++) {
      float4 av = *(const float4*)&As[kk][tn * 4];
      float4 bv = *(const float4*)&Bs[kk][tm * 4];
      float a[4] = {av.x, av.y, av.z, av.w};
      float b[4] = {bv.x, bv.y, bv.z, bv.w};
#pragma unroll
      for (int i = 0; i < 4; i++)
#pragma unroll
        for (int j = 0; j < 4; j++) acc[i][j] += a[i] * b[j];
    }
  }
#pragma unroll
  for (int i = 0; i < 4; i++) {
    int n = n0 + tn * 4 + i;
    if (n >= N) continue;
#pragma unroll
    for (int j = 0; j < 4; j++) {
      int m = m0 + tm * 4 + j;
      float v = acc[i][j];
      if (bias1) v += bias1[m];
      C[(size_t)n * M + m] = v;
    }
  }
}

// ---- top-k helpers (jax tie-break: value desc, then smaller index) ----
__device__ __forceinline__ bool tk_better(float va, int ia, float vb, int ib) {
  return (va > vb) || (va == vb && ia < ib);
}
__device__ __forceinline__ void tk_insertN(float v, int i, float* vv, int* ii) {
  if (!tk_better(v, i, vv[RT - 1], ii[RT - 1])) return;
  vv[RT - 1] = v; ii[RT - 1] = i;
#pragma unroll
  for (int q = RT - 1; q > 0; q--) {
    if (tk_better(vv[q], ii[q], vv[q - 1], ii[q - 1])) {
      float tv = vv[q]; vv[q] = vv[q - 1]; vv[q - 1] = tv;
      int ti = ii[q]; ii[q] = ii[q - 1]; ii[q - 1] = ti;
    }
  }
}
__device__ __forceinline__ void tk_merge_reg(float* av, int* ai,
                                             const float* bv2, const int* bi2) {
  float rv[RT]; int ri[RT];
  int p = 0, q = 0;
#pragma unroll
  for (int t = 0; t < RT; t++) {
    bool ta;
    if (p >= RT) ta = false;
    else if (q >= RT) ta = true;
    else ta = tk_better(av[p], ai[p], bv2[q], bi2[q]);
    if (ta) { rv[t] = av[p]; ri[t] = ai[p]; p++; }
    else    { rv[t] = bv2[q]; ri[t] = bi2[q]; q++; }
  }
#pragma unroll
  for (int t = 0; t < RT; t++) { av[t] = rv[t]; ai[t] = ri[t]; }
}
__device__ __forceinline__ void tk_merge_lds(float* sv, int* si, int a, int b) {
  float rv[RT]; int ri[RT];
  int p = 0, q = 0;
#pragma unroll
  for (int t = 0; t < RT; t++) {
    bool ta;
    if (p >= RT) ta = false;
    else if (q >= RT) ta = true;
    else ta = tk_better(sv[a + p], si[a + p], sv[b + q], si[b + q]);
    if (ta) { rv[t] = sv[a + p]; ri[t] = si[a + p]; p++; }
    else    { rv[t] = sv[b + q]; ri[t] = si[b + q]; q++; }
  }
#pragma unroll
  for (int t = 0; t < RT; t++) { sv[a + t] = rv[t]; si[a + t] = ri[t]; }
}

__device__ __forceinline__ float sigf(float x) { return 1.f / (1.f + expf(-x)); }

struct BP {
  const float *enc, *mask, *emb, *Wp, *Wv, *Wih, *Whh, *bih, *bhh, *Wc, *bc;
  float *encp, *hb, *cb, *h2, *c2, *pp, *xc, *gts, *ptv, *pmx, *psm;
  float *cumA, *cumB, *out;
  int *pti, *eosA, *eosB, *pA, *pB;
};

// ======================= phase kernels =======================

// init: ex = emb[BOS], pp = h0 @ Wp for rows 0..31. grid B_, 256 thr.
__global__ __launch_bounds__(256) void init_k(BP p)
{
  __shared__ float sF[512];
  const int b = blockIdx.x, tid = threadIdx.x;
  p.xc[(size_t)b * 768 + tid] = p.emb[(size_t)BOS_ * E_ + tid];
  sF[tid] = p.hb[(size_t)b * H_ + tid];
  sF[256 + tid] = p.hb[(size_t)b * H_ + 256 + tid];
  __syncthreads();
#pragma unroll
  for (int o = 0; o < 2; o++) {
    int m = tid + o * 256;
    float acc = 0.f;
#pragma unroll 4
    for (int k = 0; k < H_; k++) acc += sF[k] * p.Wp[(size_t)k * H_ + m];
    p.pp[(size_t)b * H_ + m] = acc;
  }
}

// AB fused: scores(tanh dot Wv, masked) -> softmax -> ctx -> xc[256..768).
// grid N blocks, 1024 threads (16 waves; wave w does s = w*16..w*16+15).
__global__ __launch_bounds__(1024) void ab_k(BP p, int t)
{
  __shared__ float ppS[512];
  __shared__ float WvS[512];
  __shared__ float aS[256];
  __shared__ float red[1024];
  const int n = blockIdx.x, tid = threadIdx.x;
  const int bdiv = t ? K_ : 1;
  const int b = n / bdiv;
  if (tid < 512) {
    ppS[tid] = p.pp[(size_t)n * H_ + tid];
    WvS[tid] = p.Wv[tid];
  }
  __syncthreads();
  const int w = tid >> 6, lane = tid & 63;
#pragma unroll
  for (int j = 0; j < 16; j++) {
    int s = w * 16 + j;
    const float* ep = p.encp + ((size_t)s * B_ + b) * H_;
    float acc = 0.f;
#pragma unroll
    for (int r = 0; r < 8; r++) {
      int hh = r * 64 + lane;
      acc += tanhf(ppS[hh] + ep[hh]) * WvS[hh];
    }
#pragma unroll
    for (int off = 32; off; off >>= 1) acc += __shfl_xor(acc, off);
    if (lane == 0)
      aS[s] = (p.mask[(size_t)b * S_ + s] == 0.f) ? NEG_ : acc;
  }
  __syncthreads();
  float v = (tid < 256) ? aS[tid] : -3.4e38f;
  red[tid] = v; __syncthreads();
  for (int st = 512; st; st >>= 1) {
    if (tid < st) red[tid] = fmaxf(red[tid], red[tid + st]);
    __syncthreads();
  }
  const float mx = red[0]; __syncthreads();
  float e = (tid < 256) ? expf(v - mx) : 0.f;
  if (tid < 256) aS[tid] = e;          // unnormalized (proven rounding pattern)
  red[tid] = e; __syncthreads();
  for (int st = 512; st; st >>= 1) {
    if (tid < st) red[tid] += red[tid + st];
    __syncthreads();
  }
  const float rsum = 1.f / red[0];
  __syncthreads();
  // ctx: col = tid&511, sg = tid>>9 covers half the s range each
  const int col = tid & 511, sg = tid >> 9;
  float acc = 0.f;
#pragma unroll 4
  for (int s0 = 0; s0 < 128; s0++) {
    int s = sg * 128 + s0;
    acc += aS[s] * p.enc[((size_t)s * B_ + b) * H_ + col];
  }
  red[tid] = acc; __syncthreads();
  if (tid < 512)
    p.xc[(size_t)n * 768 + 256 + tid] = (red[tid] + red[512 + tid]) * rsum;
}

// C: gts = [ex|ctx|h] @ [Wih;Whh], 32x64 tiles, 2 k-parts. grid 64*ntv, 256 thr.
__global__ __launch_bounds__(256) void c_k(BP p, int t)
{
  __shared__ float sF[1536];
  const int tid = threadIdx.x;
  const int N = t ? N1_ : B_;
  const int ntv = N >> 5;
  const int u = blockIdx.x;
  const int mt = u & 31;
  const int rest = u >> 5;
  const int nt = rest % ntv;
  const int kp = rest / ntv;
  const int m0 = mt * 64, n0 = nt * 32, kb = kp * 640;
  float* As = sF;
  float* Bs = sF + 512;
  const bool al = tid < 128;
  const int ar = tid & 31, ak = ((tid >> 5) & 3) * 4;
  const int bk = tid >> 4, bc4 = (tid & 15) * 4;
  const int tn = tid >> 4, tm = tid & 15;
  const int arow = n0 + ar;
  float4 aR = make_float4(0, 0, 0, 0), bR;
  {
    int k = kb + ak;
    if (al) aR = *(const float4*)((k < 768)
        ? (p.xc + (size_t)arow * 768 + k)
        : (p.hb + (size_t)arow * H_ + (k - 768)));
    int k2 = kb + bk;
    const float* Wr = (k2 < 768) ? (p.Wih + (size_t)k2 * 2048)
                                 : (p.Whh + (size_t)(k2 - 768) * 2048);
    bR = *(const float4*)(Wr + m0 + bc4);
  }
  float acc[2][4] = {};
  for (int it = 0; it < 40; it++) {
    if (it) __syncthreads();
    if (al) {
      As[(ak + 0) * 32 + ar] = aR.x; As[(ak + 1) * 32 + ar] = aR.y;
      As[(ak + 2) * 32 + ar] = aR.z; As[(ak + 3) * 32 + ar] = aR.w;
    }
    *(float4*)&Bs[bk * 64 + bc4] = bR;
    __syncthreads();
    if (it + 1 < 40) {
      int k0n = kb + (it + 1) * 16;
      int k = k0n + ak;
      if (al) aR = *(const float4*)((k < 768)
          ? (p.xc + (size_t)arow * 768 + k)
          : (p.hb + (size_t)arow * H_ + (k - 768)));
      int k2 = k0n + bk;
      const float* Wr = (k2 < 768) ? (p.Wih + (size_t)k2 * 2048)
                                   : (p.Whh + (size_t)(k2 - 768) * 2048);
      bR = *(const float4*)(Wr + m0 + bc4);
    }
#pragma unroll
    for (int kk = 0; kk < 16; kk++) {
      float a0 = As[kk * 32 + tn * 2];
      float a1 = As[kk * 32 + tn * 2 + 1];
      float4 bv = *(const float4*)&Bs[kk * 64 + tm * 4];
      acc[0][0] += a0 * bv.x; acc[0][1] += a0 * bv.y;
      acc[0][2] += a0 * bv.z; acc[0][3] += a0 * bv.w;
      acc[1][0] += a1 * bv.x; acc[1][1] += a1 * bv.y;
      acc[1][2] += a1 * bv.z; acc[1][3] += a1 * bv.w;
    }
  }
  float* gp = p.gts + (size_t)kp * GST2;
#pragma unroll
  for (int i = 0; i < 2; i++) {
    int row = n0 + tn * 2 + i;
#pragma unroll
    for (int j = 0; j < 4; j++)
      gp[(size_t)row * 2048 + m0 + tm * 4 + j] = acc[i][j];
  }
}

// D: LSTM pointwise. grid N, 256 thr.
__global__ __launch_bounds__(256) void d_k(BP p, int t)
{
  const int n = blockIdx.x, tid = threadIdx.x;
#pragma unroll
  for (int o = 0; o < 2; o++) {
    int i = tid + o * 256;
    const float* gA = p.gts + (size_t)n * 2048;
    const float* gB = p.gts + GST2 + (size_t)n * 2048;
    float gi = gA[i] + gB[i] + p.bih[i] + p.bhh[i];
    float gf = gA[512 + i] + gB[512 + i] + p.bih[512 + i] + p.bhh[512 + i];
    float gc = gA[1024 + i] + gB[1024 + i] + p.bih[1024 + i] + p.bhh[1024 + i];
    float go = gA[1536 + i] + gB[1536 + i] + p.bih[1536 + i] + p.bhh[1536 + i];
    float cc = p.cb[(size_t)n * H_ + i];
    float cv = sigf(gf) * cc + sigf(gi) * tanhf(gc);
    float hv = sigf(go) * tanhf(cv);
    p.c2[(size_t)n * H_ + i] = cv;
    p.h2[(size_t)n * H_ + i] = hv;
  }
}

// E: logits GEMM 32x128 + fused per-tile top-RT/max/expsum. grid LG_MT*ntv.
__global__ __launch_bounds__(256) void e_k(BP p, int t)
{
  __shared__ float sF[2560];
  const int tid = threadIdx.x;
  const int N = t ? N1_ : B_;
  const int u = blockIdx.x;
  const int mt = u % LG_MT, nt = u / LG_MT;
  const int m0 = mt * 128, n0 = nt * 32;
  float* As = sF;
  float* Bs = sF + 512;
  const bool al = tid < 128;
  const int ar = tid & 31, ak = ((tid >> 5) & 3) * 4;
  const int tm = tid & 31, tn = tid >> 5;
  const int arow = n0 + ar;
  const bool edge = (m0 + 128 > V_);
  float4 aR[2]; float4 bR[2][2];
#pragma unroll
  for (int d = 0; d < 2; d++) {
    int k = d * 16 + ak;
    if (al) {
      const float* src = (k < 256) ? (p.xc + (size_t)arow * 768 + k)
                       : (k < 768) ? (p.h2 + (size_t)arow * H_ + (k - 256))
                                   : (p.xc + (size_t)arow * 768 + (k - 512));
      aR[d] = *(const float4*)src;
    }
#pragma unroll
    for (int l = 0; l < 2; l++) {
      int idx = l * 256 + tid;
      int kr = d * 16 + (idx >> 5), c4 = (idx & 31) * 4;
      const float* Wr = p.Wc + (size_t)kr * V_;
      if (!edge) bR[d][l] = *(const float4*)(Wr + m0 + c4);
      else {
        float4 bv;
        bv.x = (m0 + c4 + 0 < V_) ? Wr[m0 + c4 + 0] : 0.f;
        bv.y = (m0 + c4 + 1 < V_) ? Wr[m0 + c4 + 1] : 0.f;
        bv.z = (m0 + c4 + 2 < V_) ? Wr[m0 + c4 + 2] : 0.f;
        bv.w = (m0 + c4 + 3 < V_) ? Wr[m0 + c4 + 3] : 0.f;
        bR[d][l] = bv;
      }
    }
  }
  float acc[4][4] = {};
  for (int it = 0; it < 80; it++) {
    if (it) __syncthreads();
    const int sl = it & 1;
    if (al) {
      As[(ak + 0) * 32 + ar] = aR[sl].x; As[(ak + 1) * 32 + ar] = aR[sl].y;
      As[(ak + 2) * 32 + ar] = aR[sl].z; As[(ak + 3) * 32 + ar] = aR[sl].w;
    }
#pragma unroll
    for (int l = 0; l < 2; l++) {
      int idx = l * 256 + tid;
      *(float4*)&Bs[(idx >> 5) * 128 + (idx & 31) * 4] = bR[sl][l];
    }
    __syncthreads();
    if (it + 2 < 80) {
      int k0n = (it + 2) * 16;
      int k = k0n + ak;
      if (al) {
        const float* src = (k < 256) ? (p.xc + (size_t)arow * 768 + k)
                         : (k < 768) ? (p.h2 + (size_t)arow * H_ + (k - 256))
                                     : (p.xc + (size_t)arow * 768 + (k - 512));
        aR[sl] = *(const float4*)src;
      }
#pragma unroll
      for (int l = 0; l < 2; l++) {
        int idx = l * 256 + tid;
        int kr = k0n + (idx >> 5), c4 = (idx & 31) * 4;
        const float* Wr = p.Wc + (size_t)kr * V_;
        if (!edge) bR[sl][l] = *(const float4*)(Wr + m0 + c4);
        else {
          float4 bv;
          bv.x = (m0 + c4 + 0 < V_) ? Wr[m0 + c4 + 0] : 0.f;
          bv.y = (m0 + c4 + 1 < V_) ? Wr[m0 + c4 + 1] : 0.f;
          bv.z = (m0 + c4 + 2 < V_) ? Wr[m0 + c4 + 2] : 0.f;
          bv.w = (m0 + c4 + 3 < V_) ? Wr[m0 + c4 + 3] : 0.f;
          bR[sl][l] = bv;
        }
      }
    }
#pragma unroll
    for (int kk = 0; kk < 16; kk++) {
      float4 av = *(const float4*)&As[kk * 32 + tn * 4];
      float4 bv = *(const float4*)&Bs[kk * 128 + tm * 4];
      float a[4] = {av.x, av.y, av.z, av.w};
      float b[4] = {bv.x, bv.y, bv.z, bv.w};
#pragma unroll
      for (int i = 0; i < 4; i++)
#pragma unroll
        for (int j = 0; j < 4; j++) acc[i][j] += a[i] * b[j];
    }
  }
#pragma unroll
  for (int i = 0; i < 4; i++) {
    float vv[RT]; int ii[RT];
#pragma unroll
    for (int q = 0; q < RT; q++) { vv[q] = -3.4e38f; ii[q] = 0x7fffffff; }
    float vals[4];
#pragma unroll
    for (int j = 0; j < 4; j++) {
      int m = m0 + tm * 4 + j;
      float v = (m < V_) ? (acc[i][j] + p.bc[m]) : -3.4e38f;
      vals[j] = v;
      if (m < V_) tk_insertN(v, m, vv, ii);
    }
#pragma unroll
    for (int off = 1; off < 32; off <<= 1) {
      float ov[RT]; int oi[RT];
#pragma unroll
      for (int q = 0; q < RT; q++) {
        ov[q] = __shfl_xor(vv[q], off);
        oi[q] = __shfl_xor(ii[q], off);
      }
      tk_merge_reg(vv, ii, ov, oi);
    }
    const float rowmax = vv[0];
    float s = 0.f;
#pragma unroll
    for (int j = 0; j < 4; j++) {
      int m = m0 + tm * 4 + j;
      if (m < V_) s += expf(vals[j] - rowmax);
    }
#pragma unroll
    for (int off = 1; off < 32; off <<= 1) s += __shfl_xor(s, off);
    const int gr = n0 + tn * 4 + i;
    if (tm == 0 && gr < N) {
      const size_t pb = (size_t)gr * LG_MT + mt;
#pragma unroll
      for (int q = 0; q < RT; q++) {
        p.ptv[pb * RT + q] = vv[q]; p.pti[pb * RT + q] = ii[q];
      }
      p.pmx[pb] = rowmax;
      p.psm[pb] = s;
    }
  }
}

// F: merge partials + beam select + gather + ex + next pp. grid B_, 256 thr.
__global__ __launch_bounds__(256) void f_k(BP p, int t)
{
  __shared__ float sF[2208];
  __shared__ int   sI[576];
  const int b = blockIdx.x, tid = threadIdx.x;
  const float* cumOld = (t & 1) ? p.cumA : p.cumB;
  float* cumNew = (t & 1) ? p.cumB : p.cumA;
  const int* eosOld = (t & 1) ? p.eosA : p.eosB;
  int* eosNew = (t & 1) ? p.eosB : p.eosA;
  const int* pOld = (t & 1) ? p.pA : p.pB;
  int* pNew = (t & 1) ? p.pB : p.pA;
  float* sv = sF;
  float* red = sF + 512;
  float* rtvL = sF + 640;
  float* mgL = sF + 652;
  float* lsL = sF + 656;
  float* selV = sF + 660;
  float* hL = sF + 672;
  int* si = sI;
  int* rtiL = sI + 512;
  int* selG = sI + 524;
  int* selT = sI + 528;
  const int R = t ? 3 : 1;
  for (int r = 0; r < R; r++) {
    const int row = t ? (b * K_ + r) : b;
    float mx_t = -3.4e38f, sm_t = 0.f;
    if (tid < 128) {
      float vv[RT]; int ii[RT];
#pragma unroll
      for (int q = 0; q < RT; q++) { vv[q] = -3.4e38f; ii[q] = 0x7fffffff; }
      if (tid < LG_MT) {
        const size_t pb = (size_t)row * LG_MT + tid;
#pragma unroll
        for (int q = 0; q < RT; q++) {
          vv[q] = p.ptv[pb * RT + q]; ii[q] = p.pti[pb * RT + q];
        }
        mx_t = p.pmx[pb]; sm_t = p.psm[pb];
      }
#pragma unroll
      for (int q = 0; q < RT; q++) {
        sv[tid * RT + q] = vv[q]; si[tid * RT + q] = ii[q];
      }
      red[tid] = mx_t;
    }
    __syncthreads();
    for (int st = 64; st; st >>= 1) {
      if (tid < st) {
        tk_merge_lds(sv, si, tid * RT, (tid + st) * RT);
        red[tid] = fmaxf(red[tid], red[tid + st]);
      }
      __syncthreads();
    }
    const float Mg = red[0];
    __syncthreads();
    if (tid < 128) red[tid] = sm_t * expf(mx_t - Mg);
    __syncthreads();
    for (int st = 64; st; st >>= 1) {
      if (tid < st) red[tid] += red[tid + st];
      __syncthreads();
    }
    if (tid < RT) { rtvL[r * RT + tid] = sv[tid]; rtiL[r * RT + tid] = si[tid]; }
    if (tid == 0) { mgL[r] = Mg; lsL[r] = logf(red[0]); }
    __syncthreads();
  }
  if (tid == 0) {
    if (t == 0) {
      for (int r = 0; r < K_; r++) {
        selV[r] = (rtvL[r] - mgL[0]) - lsL[0];
        selT[r] = rtiL[r];
        selG[r] = b;
      }
    } else {
      float cv[3 * RT]; int cj[3 * RT]; int cnt = 0;
      for (int k = 0; k < K_; k++) {
        int row = b * K_ + k;
        float ck = cumOld[row];
        if (eosOld[row]) {
          cv[cnt] = ck; cj[cnt] = k * V_ + EOS_; cnt++;
        } else {
          for (int q = 0; q < RT; q++) {
            cv[cnt] = ck + ((rtvL[k * RT + q] - mgL[k]) - lsL[k]);
            cj[cnt] = k * V_ + rtiL[k * RT + q]; cnt++;
          }
        }
      }
      int used = 0;
      for (int r = 0; r < K_; r++) {
        int pick = -1;
        for (int i2 = 0; i2 < cnt; i2++) {
          if ((used >> i2) & 1) continue;
          if (pick < 0 || tk_better(cv[i2], cj[i2], cv[pick], cj[pick]))
            pick = i2;
        }
        used |= 1 << pick;
        selV[r] = cv[pick];
        selG[r] = b * K_ + cj[pick] / V_;
        selT[r] = cj[pick] % V_;
      }
    }
  }
  __syncthreads();
  for (int r = 0; r < K_; r++) {
    const int n = b * K_ + r, g = selG[r], tk2 = selT[r];
#pragma unroll
    for (int o = 0; o < 2; o++) {
      int i = tid + o * 256;
      float hv = p.h2[(size_t)g * H_ + i];
      p.hb[(size_t)n * H_ + i] = hv;
      hL[r * 512 + i] = hv;
      p.cb[(size_t)n * H_ + i] = p.c2[(size_t)g * H_ + i];
    }
    p.xc[(size_t)n * 768 + tid] = p.emb[(size_t)tk2 * E_ + tid];
  }
  if (tid < 96) {
    int tt = tid / 3, r = tid % 3;
    int n = b * K_ + r, g = selG[r];
    if (t == 0) pNew[tt * N1_ + n] = (tt == 0) ? selT[r] : 0;
    else        pNew[tt * N1_ + n] = (tt == t) ? selT[r] : pOld[tt * N1_ + g];
  }
  if (tid < K_) {
    int n = b * K_ + tid;
    cumNew[n] = selV[tid];
    eosNew[n] = (t == 0) ? (selT[tid] == EOS_ ? 1 : 0)
                         : ((eosOld[selG[tid]] | (selT[tid] == EOS_)) ? 1 : 0);
  }
  __syncthreads();
  for (int oi = tid; oi < K_ * H_; oi += 256) {
    int r = oi >> 9, m = oi & 511;
    float acc = 0.f;
#pragma unroll 4
    for (int k = 0; k < H_; k++) acc += hL[r * 512 + k] * p.Wp[(size_t)k * H_ + m];
    p.pp[(size_t)(b * K_ + r) * H_ + m] = acc;
  }
}

// final output. 1 block.
__global__ __launch_bounds__(256) void out_k(BP p)
{
  const int tid = threadIdx.x;
  for (int i = tid; i < T_ * B_ + N1_; i += 256) {
    if (i < T_ * B_) {
      int tt = i >> 5, b = i & 31;
      p.out[i] = (float)p.pB[tt * N1_ + b * K_];
    } else {
      p.out[i] = p.cumB[i - T_ * B_];
    }
  }
}

// ---------------------------------------------------------------------------
extern "C" void kernel_launch(void* const* d_in, const int* in_sizes, int n_in,
                              void* d_out, int out_size, void* d_ws, size_t ws_size,
                              hipStream_t stream)
{
  const float* enc    = (const float*)d_in[0];
  const float* last_h = (const float*)d_in[1];
  const float* last_c = (const float*)d_in[2];
  const float* mask   = (const float*)d_in[3];
  const float* emb    = (const float*)d_in[5];
  const float* Wp     = (const float*)d_in[6];
  const float* We     = (const float*)d_in[7];
  const float* Wv     = (const float*)d_in[8];
  const float* W_ih   = (const float*)d_in[9];
  const float* W_hh   = (const float*)d_in[10];
  const float* b_ih   = (const float*)d_in[11];
  const float* b_hh   = (const float*)d_in[12];
  const float* Wc     = (const float*)d_in[13];
  const float* bc     = (const float*)d_in[14];
  const float* W_init = (const float*)d_in[15];
  const float* b_init = (const float*)d_in[16];

  // ws carve — ~20 MB unconditional (< proven 23.69 MB)
  float* w = (float*)d_ws;
  float* encp = w;  w += (size_t)S_ * B_ * H_;
  float* hb   = w;  w += N1_ * H_;
  float* cb   = w;  w += N1_ * H_;
  float* h2   = w;  w += N1_ * H_;
  float* c2   = w;  w += N1_ * H_;
  float* pp   = w;  w += N1_ * H_;
  float* xc   = w;  w += N1_ * 768;
  float* gts  = w;  w += 2 * GST2;
  float* ptv  = w;  w += (size_t)N1_ * LG_MT * RT;
  float* pmx  = w;  w += (size_t)N1_ * LG_MT;
  float* psm  = w;  w += (size_t)N1_ * LG_MT;
  float* cumA = w;  w += N1_;
  float* cumB = w;  w += N1_;
  int* pti  = (int*)w;  w += (size_t)N1_ * LG_MT * RT;
  int* eosA = (int*)w;  w += N1_;
  int* eosB = (int*)w;  w += N1_;
  int* pA   = (int*)w;  w += T_ * N1_;
  int* pB   = (int*)w;  w += T_ * N1_;

  // prologue: h0, c0, enc_proj
  gemm_k<<<dim3(8, 1), 256, 0, stream>>>(last_h + B_ * H_, W_init, b_init,
                                         hb, B_, H_, H_);
  gemm_k<<<dim3(8, 1), 256, 0, stream>>>(last_c + B_ * H_, W_init, b_init,
                                         cb, B_, H_, H_);
  gemm_k<<<dim3(8, 128), 256, 0, stream>>>(enc, We, nullptr,
                                           encp, S_ * B_, H_, H_);

  BP prm;
  prm.enc = enc; prm.mask = mask; prm.emb = emb; prm.Wp = Wp; prm.Wv = Wv;
  prm.Wih = W_ih; prm.Whh = W_hh; prm.bih = b_ih; prm.bhh = b_hh;
  prm.Wc = Wc; prm.bc = bc;
  prm.encp = encp; prm.hb = hb; prm.cb = cb; prm.h2 = h2; prm.c2 = c2;
  prm.pp = pp; prm.xc = xc; prm.gts = gts;
  prm.ptv = ptv; prm.pmx = pmx; prm.psm = psm;
  prm.cumA = cumA; prm.cumB = cumB; prm.out = (float*)d_out;
  prm.pti = pti; prm.eosA = eosA; prm.eosB = eosB; prm.pA = pA; prm.pB = pB;

  init_k<<<B_, 256, 0, stream>>>(prm);
  for (int t = 0; t < T_; t++) {
    const int N = t ? N1_ : B_;
    const int ntv = N >> 5;
    ab_k<<<N, 1024, 0, stream>>>(prm, t);
    c_k<<<64 * ntv, 256, 0, stream>>>(prm, t);
    d_k<<<N, 256, 0, stream>>>(prm, t);
    e_k<<<LG_MT * ntv, 256, 0, stream>>>(prm, t);
    f_k<<<B_, 256, 0, stream>>>(prm, t);
  }
  out_k<<<1, 256, 0, stream>>>(prm);
}

// Round 9
// 7121.073 us; speedup vs baseline: 2.7003x; 2.0757x over previous
//
#include <hip/hip_runtime.h>
#include <math.h>

#define S_   256
#define B_   32
#define H_   512
#define E_   256
#define V_   10000
#define K_   3
#define T_   32
#define N1_  96
#define BOS_ 1
#define EOS_ 1
#define NEG_ (-1000000000.0f)
#define RT   4
#define LG_MT2 157          // ceil(10000/64) m-tiles in logits GEMM
#define GST2 (N1_ * 2048)   // gts k-part stride (floats)

// ---------------------------------------------------------------------------
// fp32 tiled GEMM for the 3 prologue launches (h0, c0, encp). 64x64 tile.
// ---------------------------------------------------------------------------
__global__ __launch_bounds__(256) void gemm_k(
    const float* __restrict__ A, const float* __restrict__ B1,
    const float* __restrict__ bias1, float* __restrict__ C,
    int N, int Kd, int M)
{
  __shared__ float As[16][64];
  __shared__ float Bs[16][64];
  const int tid = threadIdx.x;
  const int m0 = blockIdx.x * 64;
  const int n0 = blockIdx.y * 64;
  const int tm = tid & 15, tn = tid >> 4;
  const int la_n = tid & 63;
  const int la_k = (tid >> 6) * 4;
  const int lb_m = (tid & 15) * 4;
  const int lb_k = tid >> 4;
  const int an = (n0 + la_n < N) ? (n0 + la_n) : 0;
  const float* Arow = A + (size_t)an * Kd;

  float4 a_reg = *(const float4*)(Arow + la_k);
  float4 b_reg = *(const float4*)(B1 + (size_t)lb_k * M + m0 + lb_m);
  float acc[4][4] = {};

  for (int k0 = 0; k0 < Kd; k0 += 16) {
    if (k0) __syncthreads();
    As[la_k + 0][la_n] = a_reg.x; As[la_k + 1][la_n] = a_reg.y;
    As[la_k + 2][la_n] = a_reg.z; As[la_k + 3][la_n] = a_reg.w;
    *(float4*)&Bs[lb_k][lb_m] = b_reg;
    __syncthreads();
    if (k0 + 16 < Kd) {
      a_reg = *(const float4*)(Arow + (k0 + 16) + la_k);
      b_reg = *(const float4*)(B1 + (size_t)(k0 + 16 + lb_k) * M + m0 + lb_m);
    }
#pragma unroll
    for (int kk = 0; kk < 16; kk++) {
      float4 av = *(const float4*)&As[kk][tn * 4];
      float4 bv = *(const float4*)&Bs[kk][tm * 4];
      float a[4] = {av.x, av.y, av.z, av.w};
      float b[4] = {bv.x, bv.y, bv.z, bv.w};
#pragma unroll
      for (int i = 0; i < 4; i++)
#pragma unroll
        for (int j = 0; j < 4; j++) acc[i][j] += a[i] * b[j];
    }
  }
#pragma unroll
  for (int i = 0; i < 4; i++) {
    int n = n0 + tn * 4 + i;
    if (n >= N) continue;
#pragma unroll
    for (int j = 0; j < 4; j++) {
      int m = m0 + tm * 4 + j;
      float v = acc[i][j];
      if (bias1) v += bias1[m];
      C[(size_t)n * M + m] = v;
    }
  }
}

// ---- top-k helpers (jax tie-break: value desc, then smaller index) ----
__device__ __forceinline__ bool tk_better(float va, int ia, float vb, int ib) {
  return (va > vb) || (va == vb && ia < ib);
}
__device__ __forceinline__ void tk_insertN(float v, int i, float* vv, int* ii) {
  if (!tk_better(v, i, vv[RT - 1], ii[RT - 1])) return;
  vv[RT - 1] = v; ii[RT - 1] = i;
#pragma unroll
  for (int q = RT - 1; q > 0; q--) {
    if (tk_better(vv[q], ii[q], vv[q - 1], ii[q - 1])) {
      float tv = vv[q]; vv[q] = vv[q - 1]; vv[q - 1] = tv;
      int ti = ii[q]; ii[q] = ii[q - 1]; ii[q - 1] = ti;
    }
  }
}
__device__ __forceinline__ void tk_merge_reg(float* av, int* ai,
                                             const float* bv2, const int* bi2) {
  float rv[RT]; int ri[RT];
  int p = 0, q = 0;
#pragma unroll
  for (int t = 0; t < RT; t++) {
    bool ta;
    if (p >= RT) ta = false;
    else if (q >= RT) ta = true;
    else ta = tk_better(av[p], ai[p], bv2[q], bi2[q]);
    if (ta) { rv[t] = av[p]; ri[t] = ai[p]; p++; }
    else    { rv[t] = bv2[q]; ri[t] = bi2[q]; q++; }
  }
#pragma unroll
  for (int t = 0; t < RT; t++) { av[t] = rv[t]; ai[t] = ri[t]; }
}
__device__ __forceinline__ void tk_merge_lds(float* sv, int* si, int a, int b) {
  float rv[RT]; int ri[RT];
  int p = 0, q = 0;
#pragma unroll
  for (int t = 0; t < RT; t++) {
    bool ta;
    if (p >= RT) ta = false;
    else if (q >= RT) ta = true;
    else ta = tk_better(sv[a + p], si[a + p], sv[b + q], si[b + q]);
    if (ta) { rv[t] = sv[a + p]; ri[t] = si[a + p]; p++; }
    else    { rv[t] = sv[b + q]; ri[t] = si[b + q]; q++; }
  }
#pragma unroll
  for (int t = 0; t < RT; t++) { sv[a + t] = rv[t]; si[a + t] = ri[t]; }
}

__device__ __forceinline__ float sigf(float x) { return 1.f / (1.f + expf(-x)); }

struct BP {
  const float *enc, *mask, *emb, *Wp, *Wv, *Wih, *Whh, *bih, *bhh, *Wc, *bc;
  float *encp, *hb, *cb, *h2, *c2, *pp, *sc, *xc, *gts, *ptv, *pmx, *psm;
  float *rtv, *rmax, *rlse, *cumA, *cumB, *out;
  int *pti, *rti, *tok, *eosA, *eosB, *pA, *pB;
};

// ======================= phase kernels =======================

// pp[n][m-tile] = h[n] @ Wp. grid (8, N), 256 thr. [R4-proven shape]
__global__ __launch_bounds__(256) void ppgemv_k(BP p)
{
  __shared__ float hS[512];
  __shared__ float red[256];
  const int n = blockIdx.y, tid = threadIdx.x;
  const int m = blockIdx.x * 64 + (tid & 63);
  const int kg = tid >> 6;
  hS[tid] = p.hb[(size_t)n * H_ + tid];
  hS[256 + tid] = p.hb[(size_t)n * H_ + 256 + tid];
  __syncthreads();
  float acc = 0.f;
#pragma unroll 4
  for (int k = kg * 128; k < kg * 128 + 128; k++)
    acc += hS[k] * p.Wp[(size_t)k * H_ + m];
  red[tid] = acc;
  __syncthreads();
  if (tid < 64) {
    float v = red[tid] + red[64 + tid] + red[128 + tid] + red[192 + tid];
    p.pp[(size_t)n * H_ + blockIdx.x * 64 + tid] = v;
  }
}

// Raw masked scores; stile 0 also writes ex into xc. grid (8, N), 512 thr.
__global__ __launch_bounds__(512) void score_k(BP p, int t)
{
  __shared__ float ppS[512];
  __shared__ float WvS[512];
  const int n = blockIdx.y, tid = threadIdx.x;
  const int bdiv = t ? K_ : 1;
  const int b = n / bdiv;
  ppS[tid] = p.pp[(size_t)n * H_ + tid];
  WvS[tid] = p.Wv[tid];
  if (blockIdx.x == 0 && tid < E_) {
    int tk = t ? p.tok[n] : BOS_;
    p.xc[(size_t)n * 768 + tid] = p.emb[(size_t)tk * E_ + tid];
  }
  __syncthreads();
  const int w = tid >> 6, lane = tid & 63;
#pragma unroll
  for (int j = 0; j < 4; j++) {
    int s = blockIdx.x * 32 + w * 4 + j;
    const float* ep = p.encp + ((size_t)s * B_ + b) * H_;
    float acc = 0.f;
#pragma unroll
    for (int r = 0; r < 8; r++) {
      int hh = r * 64 + lane;
      acc += tanhf(ppS[hh] + ep[hh]) * WvS[hh];
    }
#pragma unroll
    for (int off = 32; off; off >>= 1) acc += __shfl_xor(acc, off);
    if (lane == 0)
      p.sc[(size_t)n * S_ + s] =
          (p.mask[(size_t)b * S_ + s] == 0.f) ? NEG_ : acc;
  }
}

// ctx slice with in-block softmax recompute. grid (8, N), 256 thr.
__global__ __launch_bounds__(256) void ctx_k(BP p, int t)
{
  __shared__ float aS[256];
  __shared__ float red[256];
  const int n = blockIdx.y, tid = threadIdx.x;
  const int bdiv = t ? K_ : 1;
  const int b = n / bdiv;
  const int h0 = blockIdx.x * 64;
  float v = p.sc[(size_t)n * S_ + tid];
  red[tid] = v; __syncthreads();
  for (int st = 128; st; st >>= 1) {
    if (tid < st) red[tid] = fmaxf(red[tid], red[tid + st]);
    __syncthreads();
  }
  const float mx = red[0]; __syncthreads();
  float e = expf(v - mx);
  aS[tid] = e;
  red[tid] = e; __syncthreads();
  for (int st = 128; st; st >>= 1) {
    if (tid < st) red[tid] += red[tid + st];
    __syncthreads();
  }
  const float rsum = 1.f / red[0];
  __syncthreads();
  const int sg = tid >> 6, col = tid & 63;
  float acc = 0.f;
#pragma unroll 4
  for (int s0 = 0; s0 < S_; s0 += 4) {
    int s = s0 + sg;
    acc += aS[s] * p.enc[((size_t)s * B_ + b) * H_ + h0 + col];
  }
  red[tid] = acc; __syncthreads();
  if (tid < 64) {
    float tot = red[tid] + red[64 + tid] + red[128 + tid] + red[192 + tid];
    p.xc[(size_t)n * 768 + 256 + h0 + tid] = tot * rsum;
  }
}

// C: gts = [ex|ctx|h] @ [Wih;Whh], 32x64 tiles, 2 k-parts. grid 64*ntv, 256 thr.
__global__ __launch_bounds__(256) void c_k(BP p, int t)
{
  __shared__ float sF[1536];
  const int tid = threadIdx.x;
  const int N = t ? N1_ : B_;
  const int ntv = N >> 5;
  const int u = blockIdx.x;
  const int mt = u & 31;
  const int rest = u >> 5;
  const int nt = rest % ntv;
  const int kp = rest / ntv;
  const int m0 = mt * 64, n0 = nt * 32, kb = kp * 640;
  float* As = sF;
  float* Bs = sF + 512;
  const bool al = tid < 128;
  const int ar = tid & 31, ak = ((tid >> 5) & 3) * 4;
  const int bk = tid >> 4, bc4 = (tid & 15) * 4;
  const int tn = tid >> 4, tm = tid & 15;
  const int arow = n0 + ar;
  float4 aR = make_float4(0, 0, 0, 0), bR;
  {
    int k = kb + ak;
    if (al) aR = *(const float4*)((k < 768)
        ? (p.xc + (size_t)arow * 768 + k)
        : (p.hb + (size_t)arow * H_ + (k - 768)));
    int k2 = kb + bk;
    const float* Wr = (k2 < 768) ? (p.Wih + (size_t)k2 * 2048)
                                 : (p.Whh + (size_t)(k2 - 768) * 2048);
    bR = *(const float4*)(Wr + m0 + bc4);
  }
  float acc[2][4] = {};
  for (int it = 0; it < 40; it++) {
    if (it) __syncthreads();
    if (al) {
      As[(ak + 0) * 32 + ar] = aR.x; As[(ak + 1) * 32 + ar] = aR.y;
      As[(ak + 2) * 32 + ar] = aR.z; As[(ak + 3) * 32 + ar] = aR.w;
    }
    *(float4*)&Bs[bk * 64 + bc4] = bR;
    __syncthreads();
    if (it + 1 < 40) {
      int k0n = kb + (it + 1) * 16;
      int k = k0n + ak;
      if (al) aR = *(const float4*)((k < 768)
          ? (p.xc + (size_t)arow * 768 + k)
          : (p.hb + (size_t)arow * H_ + (k - 768)));
      int k2 = k0n + bk;
      const float* Wr = (k2 < 768) ? (p.Wih + (size_t)k2 * 2048)
                                   : (p.Whh + (size_t)(k2 - 768) * 2048);
      bR = *(const float4*)(Wr + m0 + bc4);
    }
#pragma unroll
    for (int kk = 0; kk < 16; kk++) {
      float a0 = As[kk * 32 + tn * 2];
      float a1 = As[kk * 32 + tn * 2 + 1];
      float4 bv = *(const float4*)&Bs[kk * 64 + tm * 4];
      acc[0][0] += a0 * bv.x; acc[0][1] += a0 * bv.y;
      acc[0][2] += a0 * bv.z; acc[0][3] += a0 * bv.w;
      acc[1][0] += a1 * bv.x; acc[1][1] += a1 * bv.y;
      acc[1][2] += a1 * bv.z; acc[1][3] += a1 * bv.w;
    }
  }
  float* gp = p.gts + (size_t)kp * GST2;
#pragma unroll
  for (int i = 0; i < 2; i++) {
    int row = n0 + tn * 2 + i;
#pragma unroll
    for (int j = 0; j < 4; j++)
      gp[(size_t)row * 2048 + m0 + tm * 4 + j] = acc[i][j];
  }
}

// D: LSTM pointwise. grid N, 256 thr.
__global__ __launch_bounds__(256) void d_k(BP p, int t)
{
  const int n = blockIdx.x, tid = threadIdx.x;
#pragma unroll
  for (int o = 0; o < 2; o++) {
    int i = tid + o * 256;
    const float* gA = p.gts + (size_t)n * 2048;
    const float* gB = p.gts + GST2 + (size_t)n * 2048;
    float gi = gA[i] + gB[i] + p.bih[i] + p.bhh[i];
    float gf = gA[512 + i] + gB[512 + i] + p.bih[512 + i] + p.bhh[512 + i];
    float gc = gA[1024 + i] + gB[1024 + i] + p.bih[1024 + i] + p.bhh[1024 + i];
    float go = gA[1536 + i] + gB[1536 + i] + p.bih[1536 + i] + p.bhh[1536 + i];
    float cc = p.cb[(size_t)n * H_ + i];
    float cv = sigf(gf) * cc + sigf(gi) * tanhf(gc);
    float hv = sigf(go) * tanhf(cv);
    p.c2[(size_t)n * H_ + i] = cv;
    p.h2[(size_t)n * H_ + i] = hv;
  }
}

// E: logits GEMM 32 rows x 64 cols + fused per-tile top-RT/max/expsum.
// grid LG_MT2 * ntv = 471 blocks at t>=1 (~1.84 blocks/CU). 256 thr.
// Thread tile 4 rows x 2 cols (tn=tid>>5 rowgrp, tm=tid&31 colgrp).
__global__ __launch_bounds__(256) void e_k(BP p, int t)
{
  __shared__ float As[16 * 32];
  __shared__ float Bs[16 * 64];
  const int tid = threadIdx.x;
  const int N = t ? N1_ : B_;
  const int u = blockIdx.x;
  const int mt = u % LG_MT2, nt = u / LG_MT2;
  const int m0 = mt * 64, n0 = nt * 32;
  const bool al = tid < 128;
  const int ar = tid & 31, ak = ((tid >> 5) & 3) * 4;
  const int bkr = tid >> 4, bc4 = (tid & 15) * 4;
  const int tn = tid >> 5, tm = tid & 31;
  const int arow = n0 + ar;
  const bool edge = (m0 + 64 > V_);

  float4 aR[2]; float4 bR[2];
#pragma unroll
  for (int d = 0; d < 2; d++) {
    int k = d * 16 + ak;
    if (al) {
      const float* src = (k < 256) ? (p.xc + (size_t)arow * 768 + k)
                       : (k < 768) ? (p.h2 + (size_t)arow * H_ + (k - 256))
                                   : (p.xc + (size_t)arow * 768 + (k - 512));
      aR[d] = *(const float4*)src;
    }
    int kr = d * 16 + bkr;
    const float* Wr = p.Wc + (size_t)kr * V_;
    if (!edge) bR[d] = *(const float4*)(Wr + m0 + bc4);
    else {
      float4 bv;
      bv.x = (m0 + bc4 + 0 < V_) ? Wr[m0 + bc4 + 0] : 0.f;
      bv.y = (m0 + bc4 + 1 < V_) ? Wr[m0 + bc4 + 1] : 0.f;
      bv.z = (m0 + bc4 + 2 < V_) ? Wr[m0 + bc4 + 2] : 0.f;
      bv.w = (m0 + bc4 + 3 < V_) ? Wr[m0 + bc4 + 3] : 0.f;
      bR[d] = bv;
    }
  }

  float acc[4][2] = {};
  for (int it = 0; it < 80; it++) {
    if (it) __syncthreads();
    const int sl = it & 1;
    if (al) {
      As[(ak + 0) * 32 + ar] = aR[sl].x; As[(ak + 1) * 32 + ar] = aR[sl].y;
      As[(ak + 2) * 32 + ar] = aR[sl].z; As[(ak + 3) * 32 + ar] = aR[sl].w;
    }
    *(float4*)&Bs[bkr * 64 + bc4] = bR[sl];
    __syncthreads();
    if (it + 2 < 80) {
      int k0n = (it + 2) * 16;
      int k = k0n + ak;
      if (al) {
        const float* src = (k < 256) ? (p.xc + (size_t)arow * 768 + k)
                         : (k < 768) ? (p.h2 + (size_t)arow * H_ + (k - 256))
                                     : (p.xc + (size_t)arow * 768 + (k - 512));
        aR[sl] = *(const float4*)src;
      }
      int kr = k0n + bkr;
      const float* Wr = p.Wc + (size_t)kr * V_;
      if (!edge) bR[sl] = *(const float4*)(Wr + m0 + bc4);
      else {
        float4 bv;
        bv.x = (m0 + bc4 + 0 < V_) ? Wr[m0 + bc4 + 0] : 0.f;
        bv.y = (m0 + bc4 + 1 < V_) ? Wr[m0 + bc4 + 1] : 0.f;
        bv.z = (m0 + bc4 + 2 < V_) ? Wr[m0 + bc4 + 2] : 0.f;
        bv.w = (m0 + bc4 + 3 < V_) ? Wr[m0 + bc4 + 3] : 0.f;
        bR[sl] = bv;
      }
    }
#pragma unroll
    for (int kk = 0; kk < 16; kk++) {
      float4 av = *(const float4*)&As[kk * 32 + tn * 4];
      float2 bv = *(const float2*)&Bs[kk * 64 + tm * 2];
      float a[4] = {av.x, av.y, av.z, av.w};
#pragma unroll
      for (int i = 0; i < 4; i++) {
        acc[i][0] += a[i] * bv.x;
        acc[i][1] += a[i] * bv.y;
      }
    }
  }

  // fused epilogue: per-row (this 64-col tile) top-RT, max, expsum
#pragma unroll
  for (int i = 0; i < 4; i++) {
    float vv[RT]; int ii[RT];
#pragma unroll
    for (int q = 0; q < RT; q++) { vv[q] = -3.4e38f; ii[q] = 0x7fffffff; }
    float vals[2];
#pragma unroll
    for (int j = 0; j < 2; j++) {
      int m = m0 + tm * 2 + j;
      float v = (m < V_) ? (acc[i][j] + p.bc[m]) : -3.4e38f;
      vals[j] = v;
      if (m < V_) tk_insertN(v, m, vv, ii);
    }
#pragma unroll
    for (int off = 1; off < 32; off <<= 1) {
      float ov[RT]; int oi[RT];
#pragma unroll
      for (int q = 0; q < RT; q++) {
        ov[q] = __shfl_xor(vv[q], off);
        oi[q] = __shfl_xor(ii[q], off);
      }
      tk_merge_reg(vv, ii, ov, oi);
    }
    const float rowmax = vv[0];
    float s = 0.f;
#pragma unroll
    for (int j = 0; j < 2; j++) {
      int m = m0 + tm * 2 + j;
      if (m < V_) s += expf(vals[j] - rowmax);
    }
#pragma unroll
    for (int off = 1; off < 32; off <<= 1) s += __shfl_xor(s, off);
    const int gr = n0 + tn * 4 + i;
    if (tm == 0 && gr < N) {
      const size_t pb = (size_t)gr * LG_MT2 + mt;
#pragma unroll
      for (int q = 0; q < RT; q++) {
        p.ptv[pb * RT + q] = vv[q]; p.pti[pb * RT + q] = ii[q];
      }
      p.pmx[pb] = rowmax;
      p.psm[pb] = s;
    }
  }
}

// Merge LG_MT2 per-tile partials per row -> rtv/rti/rmax/rlse. grid N, 256 thr.
__global__ __launch_bounds__(256) void lgm_k(BP p, int t)
{
  __shared__ float sv[256 * RT];
  __shared__ int si[256 * RT];
  __shared__ float red[256];
  const int n = blockIdx.x, tid = threadIdx.x;
  float mx_t = -3.4e38f, sm_t = 0.f;
  float vv[RT]; int ii[RT];
#pragma unroll
  for (int q = 0; q < RT; q++) { vv[q] = -3.4e38f; ii[q] = 0x7fffffff; }
  if (tid < LG_MT2) {
    const size_t pb = (size_t)n * LG_MT2 + tid;
#pragma unroll
    for (int q = 0; q < RT; q++) { vv[q] = p.ptv[pb * RT + q]; ii[q] = p.pti[pb * RT + q]; }
    mx_t = p.pmx[pb]; sm_t = p.psm[pb];
  }
#pragma unroll
  for (int q = 0; q < RT; q++) { sv[tid * RT + q] = vv[q]; si[tid * RT + q] = ii[q]; }
  red[tid] = mx_t;
  __syncthreads();
  for (int st = 128; st; st >>= 1) {
    if (tid < st) {
      tk_merge_lds(sv, si, tid * RT, (tid + st) * RT);
      red[tid] = fmaxf(red[tid], red[tid + st]);
    }
    __syncthreads();
  }
  const float Mg = red[0];
  __syncthreads();
  red[tid] = (sm_t > 0.f) ? sm_t * expf(mx_t - Mg) : 0.f;
  __syncthreads();
  for (int st = 128; st; st >>= 1) {
    if (tid < st) red[tid] += red[tid + st];
    __syncthreads();
  }
  if (tid < RT) { p.rtv[n * RT + tid] = sv[tid]; p.rti[n * RT + tid] = si[tid]; }
  if (tid == 0) { p.rmax[n] = Mg; p.rlse[n] = logf(red[0]); }
}

// step-0: beam expand + init. grid 96. [R5-proven]
__global__ __launch_bounds__(256) void reorder0_k(BP p)
{
  const int n = blockIdx.x, b = n / K_, r = n % K_, tid = threadIdx.x;
  for (int i = tid; i < H_; i += 256) {
    p.hb[(size_t)n * H_ + i] = p.h2[(size_t)b * H_ + i];
    p.cb[(size_t)n * H_ + i] = p.c2[(size_t)b * H_ + i];
  }
  if (tid < T_) p.pA[tid * N1_ + n] = 0;
  if (tid == 0) {
    float val = (p.rtv[b * RT + r] - p.rmax[b]) - p.rlse[b];
    int idx = p.rti[b * RT + r];
    p.pA[n] = idx;
    p.cumA[n] = val; p.tok[n] = idx; p.eosA[n] = (idx == EOS_) ? 1 : 0;
  }
}

// step-t: 12-candidate exact merge + gather. grid 96. [R5-proven]
__global__ __launch_bounds__(256) void reorder1_k(BP p, int t)
{
  __shared__ int s_g, s_tok;
  __shared__ float s_val;
  const int n = blockIdx.x, b = n / K_, r = n % K_, tid = threadIdx.x;
  const float* cumOld = (t & 1) ? p.cumA : p.cumB;
  float* cumNew = (t & 1) ? p.cumB : p.cumA;
  const int* eosOld = (t & 1) ? p.eosA : p.eosB;
  int* eosNew = (t & 1) ? p.eosB : p.eosA;
  const int* pOld = (t & 1) ? p.pA : p.pB;
  int* pNew = (t & 1) ? p.pB : p.pA;
  if (tid == 0) {
    float cv[3 * RT]; int cj[3 * RT]; int cnt = 0;
    for (int k = 0; k < K_; k++) {
      int row = b * K_ + k;
      float ck = cumOld[row];
      if (eosOld[row]) {
        cv[cnt] = ck; cj[cnt] = k * V_ + EOS_; cnt++;
      } else {
        float mxk = p.rmax[row], lsk = p.rlse[row];
        for (int q = 0; q < RT; q++) {
          cv[cnt] = ck + ((p.rtv[row * RT + q] - mxk) - lsk);
          cj[cnt] = k * V_ + p.rti[row * RT + q]; cnt++;
        }
      }
    }
    int used = 0, pick = -1;
    for (int rep = 0; rep <= r; rep++) {
      pick = -1;
      for (int i2 = 0; i2 < cnt; i2++) {
        if ((used >> i2) & 1) continue;
        if (pick < 0 || tk_better(cv[i2], cj[i2], cv[pick], cj[pick])) pick = i2;
      }
      used |= 1 << pick;
    }
    int j = cj[pick];
    s_val = cv[pick];
    s_g = b * K_ + j / V_;
    s_tok = j % V_;
  }
  __syncthreads();
  const int g = s_g, ntok = s_tok;
  for (int i = tid; i < H_; i += 256) {
    p.hb[(size_t)n * H_ + i] = p.h2[(size_t)g * H_ + i];
    p.cb[(size_t)n * H_ + i] = p.c2[(size_t)g * H_ + i];
  }
  if (tid < T_) pNew[tid * N1_ + n] = (tid == t) ? ntok : pOld[tid * N1_ + g];
  if (tid == 0) {
    cumNew[n] = s_val;
    eosNew[n] = eosOld[g] | (ntok == EOS_ ? 1 : 0);
    p.tok[n] = ntok;
  }
}

// final output. 1 block.
__global__ __launch_bounds__(256) void out_k(BP p)
{
  const int tid = threadIdx.x;
  for (int i = tid; i < T_ * B_ + N1_; i += 256) {
    if (i < T_ * B_) {
      int tt = i >> 5, b = i & 31;
      p.out[i] = (float)p.pB[tt * N1_ + b * K_];
    } else {
      p.out[i] = p.cumB[i - T_ * B_];
    }
  }
}

// ---------------------------------------------------------------------------
extern "C" void kernel_launch(void* const* d_in, const int* in_sizes, int n_in,
                              void* d_out, int out_size, void* d_ws, size_t ws_size,
                              hipStream_t stream)
{
  const float* enc    = (const float*)d_in[0];
  const float* last_h = (const float*)d_in[1];
  const float* last_c = (const float*)d_in[2];
  const float* mask   = (const float*)d_in[3];
  const float* emb    = (const float*)d_in[5];
  const float* Wp     = (const float*)d_in[6];
  const float* We     = (const float*)d_in[7];
  const float* Wv     = (const float*)d_in[8];
  const float* W_ih   = (const float*)d_in[9];
  const float* W_hh   = (const float*)d_in[10];
  const float* b_ih   = (const float*)d_in[11];
  const float* b_hh   = (const float*)d_in[12];
  const float* Wc     = (const float*)d_in[13];
  const float* bc     = (const float*)d_in[14];
  const float* W_init = (const float*)d_in[15];
  const float* b_init = (const float*)d_in[16];

  // ws carve — ~20.5 MB unconditional (< proven-safe 23.69 MB)
  float* w = (float*)d_ws;
  float* encp = w;  w += (size_t)S_ * B_ * H_;
  float* hb   = w;  w += N1_ * H_;
  float* cb   = w;  w += N1_ * H_;
  float* h2   = w;  w += N1_ * H_;
  float* c2   = w;  w += N1_ * H_;
  float* pp   = w;  w += N1_ * H_;
  float* sc   = w;  w += N1_ * S_;
  float* xc   = w;  w += N1_ * 768;
  float* gts  = w;  w += 2 * GST2;
  float* ptv  = w;  w += (size_t)N1_ * LG_MT2 * RT;
  float* pmx  = w;  w += (size_t)N1_ * LG_MT2;
  float* psm  = w;  w += (size_t)N1_ * LG_MT2;
  float* rtv  = w;  w += N1_ * RT;
  float* rmax = w;  w += N1_;
  float* rlse = w;  w += N1_;
  float* cumA = w;  w += N1_;
  float* cumB = w;  w += N1_;
  int* pti  = (int*)w;  w += (size_t)N1_ * LG_MT2 * RT;
  int* rti  = (int*)w;  w += N1_ * RT;
  int* tok  = (int*)w;  w += N1_;
  int* eosA = (int*)w;  w += N1_;
  int* eosB = (int*)w;  w += N1_;
  int* pA   = (int*)w;  w += T_ * N1_;
  int* pB   = (int*)w;  w += T_ * N1_;

  // prologue: h0, c0, enc_proj
  gemm_k<<<dim3(8, 1), 256, 0, stream>>>(last_h + B_ * H_, W_init, b_init,
                                         hb, B_, H_, H_);
  gemm_k<<<dim3(8, 1), 256, 0, stream>>>(last_c + B_ * H_, W_init, b_init,
                                         cb, B_, H_, H_);
  gemm_k<<<dim3(8, 128), 256, 0, stream>>>(enc, We, nullptr,
                                           encp, S_ * B_, H_, H_);

  BP prm;
  prm.enc = enc; prm.mask = mask; prm.emb = emb; prm.Wp = Wp; prm.Wv = Wv;
  prm.Wih = W_ih; prm.Whh = W_hh; prm.bih = b_ih; prm.bhh = b_hh;
  prm.Wc = Wc; prm.bc = bc;
  prm.encp = encp; prm.hb = hb; prm.cb = cb; prm.h2 = h2; prm.c2 = c2;
  prm.pp = pp; prm.sc = sc; prm.xc = xc; prm.gts = gts;
  prm.ptv = ptv; prm.pmx = pmx; prm.psm = psm;
  prm.rtv = rtv; prm.rmax = rmax; prm.rlse = rlse;
  prm.cumA = cumA; prm.cumB = cumB; prm.out = (float*)d_out;
  prm.pti = pti; prm.rti = rti; prm.tok = tok;
  prm.eosA = eosA; prm.eosB = eosB; prm.pA = pA; prm.pB = pB;

  for (int t = 0; t < T_; t++) {
    const int N = t ? N1_ : B_;
    const int ntv = N >> 5;
    ppgemv_k<<<dim3(8, N), 256, 0, stream>>>(prm);
    score_k<<<dim3(8, N), 512, 0, stream>>>(prm, t);
    ctx_k<<<dim3(8, N), 256, 0, stream>>>(prm, t);
    c_k<<<64 * ntv, 256, 0, stream>>>(prm, t);
    d_k<<<N, 256, 0, stream>>>(prm, t);
    e_k<<<LG_MT2 * ntv, 256, 0, stream>>>(prm, t);
    lgm_k<<<N, 256, 0, stream>>>(prm, t);
    if (t == 0) reorder0_k<<<N1_, 256, 0, stream>>>(prm);
    else        reorder1_k<<<N1_, 256, 0, stream>>>(prm, t);
  }
  out_k<<<1, 256, 0, stream>>>(prm);
}